// Round 5
// baseline (419.343 us; speedup 1.0000x reference)
//
#include <hip/hip_runtime.h>
#include <cmath>

#define BB   2
#define SS   1024
#define DIMM 3072
#define NHH  24
#define HDD  128
#define MM   (BB * SS)

typedef _Float16 f16;
typedef __attribute__((ext_vector_type(8))) _Float16 half8;
typedef __attribute__((ext_vector_type(4))) float floatx4;
typedef unsigned int u32;
typedef const __attribute__((address_space(1))) u32* gp1;
typedef __attribute__((address_space(3))) u32* lp3;

__device__ __forceinline__ void gload_lds16(const void* g, void* l) {
    __builtin_amdgcn_global_load_lds((gp1)g, (lp3)l, 16, 0, 0);
}

// ---------------- fp32 -> fp16 converter ----------------
__global__ __launch_bounds__(256) void cvt_f16_kernel(
    const float* __restrict__ in, f16* __restrict__ outp, int n8)
{
    int i = blockIdx.x * 256 + threadIdx.x;
    if (i >= n8) return;
    const float4* p = (const float4*)(in + (size_t)i * 8);
    float4 a = p[0], b = p[1];
    half8 h = {(f16)a.x, (f16)a.y, (f16)a.z, (f16)a.w,
               (f16)b.x, (f16)b.y, (f16)b.z, (f16)b.w};
    *(half8*)(outp + (size_t)i * 8) = h;
}

// ---------------- GEMM: C = A16 @ W^T + bias (f16 MFMA, fp32 accum) ----------------
// Double-buffered LDS, 1 barrier per K-step; A via global_load_lds (pre-swizzled
// source), B reg-staged fp32 -> f16 (issue-early / convert-late).
template<bool QKV>
__global__ __launch_bounds__(256, 3) void gemm_f16(
    const f16* __restrict__ A,
    const float* __restrict__ W0, const float* __restrict__ W1, const float* __restrict__ W2,
    const float* __restrict__ b0, const float* __restrict__ b1, const float* __restrict__ b2,
    f16* __restrict__ D0, f16* __restrict__ D1, f16* __restrict__ D2,
    float* __restrict__ F)
{
    constexpr int K = DIMM;
    constexpr int NSTEP = K / 32;
    __shared__ f16 As[2][128 * 32];
    __shared__ f16 Bs[2][128 * 32];

    const int tid  = threadIdx.x;
    const int lane = tid & 63;
    const int wave = tid >> 6;
    const int wm = wave >> 1, wn = wave & 1;
    const int lr = lane & 15;
    const int lq = lane >> 4;

    // bijective XCD swizzle (grid % 8 == 0 for both 1152 and 384)
    const int id  = blockIdx.x;
    const int cpx = (int)gridDim.x >> 3;
    const int swz = (id & 7) * cpx + (id >> 3);
    const int bm = (swz & 15) << 7;        // 16 M-tiles
    const int bn = (swz >> 4) << 7;

    const float* W; const float* bias; f16* D = nullptr;
    int nloc = bn;
    if constexpr (QKV) {
        int sel = bn / DIMM;
        nloc = bn - sel * DIMM;
        W    = sel == 0 ? W0 : (sel == 1 ? W1 : W2);
        bias = sel == 0 ? b0 : (sel == 1 ? b1 : b2);
        D    = sel == 0 ? D0 : (sel == 1 ? D1 : D2);
    } else { W = W0; bias = b0; }

    // ---- B staging coords (rows r0, r0+64; col chunk c8, XOR-swizzled by row&3) ----
    const int r0 = tid >> 2;
    const int c8 = (tid & 3) << 3;
    const int c8sw = c8 ^ ((r0 & 3) << 3);   // LDS slot for this thread's chunk
    const float* bp0 = W + (size_t)(nloc + r0) * K + c8;
    const float* bp1 = W + (size_t)(nloc + r0 + 64) * K + c8;

    // ---- A staging via global_load_lds: LDS is linear; global source pre-swizzled ----
    const int arow_l = lane >> 2;                       // 0..15
    const int acol_sw = (((lane & 3) ^ (arow_l & 3)) << 3);  // pre-swizzled source chunk
    const f16* agbase = A + (size_t)bm * K;

    float4 sb00, sb01, sb10, sb11;
    auto LOADB = [&](int k0) {
        sb00 = *(const float4*)(bp0 + k0); sb01 = *(const float4*)(bp0 + k0 + 4);
        sb10 = *(const float4*)(bp1 + k0); sb11 = *(const float4*)(bp1 + k0 + 4);
    };
    auto STOREB = [&](int buf) {
        half8 h0 = {(f16)sb00.x, (f16)sb00.y, (f16)sb00.z, (f16)sb00.w,
                    (f16)sb01.x, (f16)sb01.y, (f16)sb01.z, (f16)sb01.w};
        half8 h1 = {(f16)sb10.x, (f16)sb10.y, (f16)sb10.z, (f16)sb10.w,
                    (f16)sb11.x, (f16)sb11.y, (f16)sb11.z, (f16)sb11.w};
        *(half8*)&Bs[buf][r0 * 32 + c8sw]        = h0;
        *(half8*)&Bs[buf][(r0 + 64) * 32 + c8sw] = h1;   // (r0+64)&3 == r0&3
    };
    auto STAGEA = [&](int k0, int buf) {
#pragma unroll
        for (int i = 0; i < 2; ++i) {
            int rbase = wave * 32 + i * 16;
            gload_lds16(agbase + (size_t)(rbase + arow_l) * K + k0 + acol_sw,
                        &As[buf][rbase * 32]);
        }
    };

    floatx4 acc[4][4];
#pragma unroll
    for (int i = 0; i < 4; ++i)
#pragma unroll
        for (int j = 0; j < 4; ++j) acc[i][j] = (floatx4){0.f, 0.f, 0.f, 0.f};

    // prologue: stage K-step 0 into buf 0
    STAGEA(0, 0);
    LOADB(0);
    STOREB(0);
    __syncthreads();

    for (int ks = 0; ks < NSTEP; ++ks) {
        const int cur = ks & 1, nxt = cur ^ 1;
        const bool more = (ks + 1 < NSTEP);
        if (more) {
            STAGEA((ks + 1) * 32, nxt);     // async DMA flies under MFMA
            LOADB((ks + 1) * 32);           // B loads fly under MFMA
        }

        half8 af[4], bf[4];
#pragma unroll
        for (int i = 0; i < 4; ++i) {
            int ra = wm * 64 + i * 16 + lr;
            int rb = wn * 64 + i * 16 + lr;
            af[i] = *(const half8*)&As[cur][ra * 32 + ((lq << 3) ^ ((ra & 3) << 3))];
            bf[i] = *(const half8*)&Bs[cur][rb * 32 + ((lq << 3) ^ ((rb & 3) << 3))];
        }
#pragma unroll
        for (int mi = 0; mi < 4; ++mi)
#pragma unroll
            for (int ni = 0; ni < 4; ++ni)
                acc[mi][ni] = __builtin_amdgcn_mfma_f32_16x16x32_f16(af[mi], bf[ni], acc[mi][ni], 0, 0, 0);

        if (more) STOREB(nxt);              // cvt+LDS-write after MFMA, before barrier
        __syncthreads();                    // drains gload_lds for nxt too
    }

    // epilogue: C/D layout col = lane&15, row = (lane>>4)*4 + reg
    const int crow0 = bm + wm * 64 + (lq << 2);
    const int ccol0 = nloc + wn * 64;
#pragma unroll
    for (int ni = 0; ni < 4; ++ni) {
        const int col = ccol0 + ni * 16 + lr;
        const float bv = bias[col];
#pragma unroll
        for (int mi = 0; mi < 4; ++mi) {
            const int row = crow0 + mi * 16;
#pragma unroll
            for (int r2 = 0; r2 < 4; ++r2) {
                if constexpr (QKV)
                    D[(size_t)(row + r2) * DIMM + col] = (f16)(acc[mi][ni][r2] + bv);
                else
                    F[(size_t)(row + r2) * DIMM + col] = acc[mi][ni][r2] + bv;
            }
        }
    }
}

// ---------------- RMSNorm (over 3072) + RoPE, f16 in/out ----------------
__global__ __launch_bounds__(192) void rmsnorm_rope_f16(
    f16* __restrict__ q, f16* __restrict__ k,
    const float* __restrict__ gq, const float* __restrict__ gk,
    const float* __restrict__ freqs)
{
    f16* t = (blockIdx.y == 0) ? q : k;
    const float* g = (blockIdx.y == 0) ? gq : gk;
    const int row = blockIdx.x;
    const int s = row & (SS - 1);
    const int tid = threadIdx.x;
    f16* base = t + (size_t)row * DIMM + tid * 16;

    half8 v0 = *(const half8*)base;
    half8 v1 = *(const half8*)(base + 8);
    float v[16];
#pragma unroll
    for (int j = 0; j < 8; ++j) { v[j] = (float)v0[j]; v[8 + j] = (float)v1[j]; }

    float ssq = 0.f;
#pragma unroll
    for (int j = 0; j < 16; ++j) ssq += v[j] * v[j];
#pragma unroll
    for (int off = 32; off > 0; off >>= 1) ssq += __shfl_down(ssq, off, 64);
    __shared__ float red[3];
    if ((tid & 63) == 0) red[tid >> 6] = ssq;
    __syncthreads();
    float tot = red[0] + red[1] + red[2];
    float sc = rsqrtf(tot * (1.0f / (float)DIMM) + 1e-6f);

    const float* gp = g + tid * 16;
    float y[16];
#pragma unroll
    for (int j = 0; j < 16; ++j) y[j] = v[j] * sc * gp[j];

#pragma unroll
    for (int p = 0; p < 8; ++p) {
        int idx = tid * 16 + 2 * p;
        int f = (idx & 127) >> 1;
        float ang = freqs[s * 64 + f];
        float cc = cosf(ang), sn = sinf(ang);
        float e = y[2 * p], o = y[2 * p + 1];
        y[2 * p]     = e * cc - o * sn;
        y[2 * p + 1] = e * sn + o * cc;
    }
    half8 o0, o1;
#pragma unroll
    for (int j = 0; j < 8; ++j) { o0[j] = (f16)y[j]; o1[j] = (f16)y[8 + j]; }
    *(half8*)base       = o0;
    *(half8*)(base + 8) = o1;
}

// ---------------- Flash attention: f16 MFMA, wave-parallel online softmax ----------------
__global__ __launch_bounds__(256) void flash_attn_f16(
    const f16* __restrict__ Q, const f16* __restrict__ K,
    const f16* __restrict__ V, const int* __restrict__ seq_lens,
    f16* __restrict__ O)
{
    __shared__ f16 QPs[64 * 128];   // Q tile; wave regions reused as P buffer
    __shared__ f16 Ks[64 * 128];
    __shared__ f16 Vt[128 * 64];    // V transposed [d][j], swizzled

    const int tid  = threadIdx.x;
    const int lane = tid & 63;
    const int wave = tid >> 6;
    const int ln = lane & 15;
    const int lq = lane >> 4;
    const int i0 = blockIdx.x * 64;
    const int h  = blockIdx.y;
    const int b  = blockIdx.z;
    const int slen = seq_lens[b];
    const float scale = 0.08838834764831845f;
    const size_t gstride = NHH * HDD;

    const f16* Qg = Q + ((size_t)(b * SS + i0) * NHH + h) * HDD;
#pragma unroll
    for (int rep = 0; rep < 4; ++rep) {
        int u = tid + rep * 256;
        int r = u >> 4, d0 = (u & 15) << 3;
        half8 qv = *(const half8*)(Qg + (size_t)r * gstride + d0);
        *(half8*)(QPs + r * 128 + (d0 ^ ((r & 7) << 3))) = qv;
    }
    __syncthreads();

    half8 qfrag[4];
    {
        int rq = wave * 16 + ln;
#pragma unroll
        for (int ks = 0; ks < 4; ++ks)
            qfrag[ks] = *(const half8*)(QPs + rq * 128 + ((ks * 32 + lq * 8) ^ ((rq & 7) << 3)));
    }

    floatx4 accO[8];
#pragma unroll
    for (int dt = 0; dt < 8; ++dt) accO[dt] = (floatx4){0.f, 0.f, 0.f, 0.f};
    float mrow[4] = {-3.0e38f, -3.0e38f, -3.0e38f, -3.0e38f};
    float lrow[4] = {0.f, 0.f, 0.f, 0.f};

    const int nT = (slen + 63) >> 6;
    for (int t = 0; t < nT; ++t) {
        const int j0g = t * 64;
        __syncthreads();

        const f16* Kg = K + ((size_t)(b * SS + j0g) * NHH + h) * HDD;
#pragma unroll
        for (int rep = 0; rep < 4; ++rep) {
            int u = tid + rep * 256;
            int r = u >> 4, d0 = (u & 15) << 3;
            half8 kv = *(const half8*)(Kg + (size_t)r * gstride + d0);
            *(half8*)(Ks + r * 128 + (d0 ^ ((r & 7) << 3))) = kv;
        }
        const f16* Vg = V + ((size_t)(b * SS + j0g) * NHH + h) * HDD;
#pragma unroll
        for (int rep = 0; rep < 2; ++rep) {
            int u = tid + rep * 256;
            int jp = u & 31, j0 = jp * 2;
            int d0 = (u >> 5) << 3;
            half8 va = *(const half8*)(Vg + (size_t)j0 * gstride + d0);
            half8 vb = *(const half8*)(Vg + (size_t)(j0 + 1) * gstride + d0);
#pragma unroll
            for (int i = 0; i < 8; ++i) {
                int d = d0 + i;
                union { f16 h[2]; u32 w; } pk;
                pk.h[0] = va[i]; pk.h[1] = vb[i];
                *(u32*)(Vt + d * 64 + (j0 ^ ((d & 7) << 3))) = pk.w;
            }
        }
        __syncthreads();

        // QK^T
        floatx4 acc_s[4];
#pragma unroll
        for (int nt = 0; nt < 4; ++nt) {
            acc_s[nt] = (floatx4){0.f, 0.f, 0.f, 0.f};
            int rk = nt * 16 + ln;
#pragma unroll
            for (int ks = 0; ks < 4; ++ks) {
                half8 kf = *(const half8*)(Ks + rk * 128 + ((ks * 32 + lq * 8) ^ ((rk & 7) << 3)));
                acc_s[nt] = __builtin_amdgcn_mfma_f32_16x16x32_f16(qfrag[ks], kf, acc_s[nt], 0, 0, 0);
            }
        }

        // online softmax (rows = lq*4 + r of this wave's 16)
        float s[4][4];
#pragma unroll
        for (int nt = 0; nt < 4; ++nt) {
            int j = j0g + nt * 16 + ln;
            bool valid = (j < slen);
#pragma unroll
            for (int r = 0; r < 4; ++r)
                s[nt][r] = valid ? acc_s[nt][r] * scale : -3.0e38f;
        }
        float fct[4];
#pragma unroll
        for (int r = 0; r < 4; ++r) {
            float m4 = fmaxf(fmaxf(s[0][r], s[1][r]), fmaxf(s[2][r], s[3][r]));
            m4 = fmaxf(m4, __shfl_xor(m4, 1, 64));
            m4 = fmaxf(m4, __shfl_xor(m4, 2, 64));
            m4 = fmaxf(m4, __shfl_xor(m4, 4, 64));
            m4 = fmaxf(m4, __shfl_xor(m4, 8, 64));
            float mn = fmaxf(mrow[r], m4);
            fct[r] = __expf(mrow[r] - mn);
            mrow[r] = mn;
            float ls = 0.f;
#pragma unroll
            for (int nt = 0; nt < 4; ++nt) {
                float p = __expf(s[nt][r] - mn);
                s[nt][r] = p;
                ls += p;
            }
            ls += __shfl_xor(ls, 1, 64);
            ls += __shfl_xor(ls, 2, 64);
            ls += __shfl_xor(ls, 4, 64);
            ls += __shfl_xor(ls, 8, 64);
            lrow[r] = lrow[r] * fct[r] + ls;
        }

        // write P (f16) into this wave's private region of QPs
#pragma unroll
        for (int nt = 0; nt < 4; ++nt) {
#pragma unroll
            for (int r = 0; r < 4; ++r) {
                int rw = lq * 4 + r;
                int j = nt * 16 + ln;
                QPs[(wave * 16 + rw) * 128 + (j ^ ((rw & 7) << 3))] = (f16)s[nt][r];
            }
        }

        // rescale O
#pragma unroll
        for (int dt = 0; dt < 8; ++dt)
#pragma unroll
            for (int r = 0; r < 4; ++r) accO[dt][r] *= fct[r];

        // PV
        half8 pfrag[2];
#pragma unroll
        for (int js = 0; js < 2; ++js)
            pfrag[js] = *(const half8*)(QPs + (wave * 16 + ln) * 128 + ((js * 32 + lq * 8) ^ ((ln & 7) << 3)));
#pragma unroll
        for (int dt = 0; dt < 8; ++dt) {
            int d = dt * 16 + ln;
#pragma unroll
            for (int js = 0; js < 2; ++js) {
                half8 vf = *(const half8*)(Vt + d * 64 + ((js * 32 + lq * 8) ^ ((d & 7) << 3)));
                accO[dt] = __builtin_amdgcn_mfma_f32_16x16x32_f16(pfrag[js], vf, accO[dt], 0, 0, 0);
            }
        }
    }

    // finalize: /l, write O (f16)
    float linv[4];
#pragma unroll
    for (int r = 0; r < 4; ++r) linv[r] = 1.0f / lrow[r];
    f16* Og = O + ((size_t)(b * SS + i0) * NHH + h) * HDD;
#pragma unroll
    for (int dt = 0; dt < 8; ++dt) {
#pragma unroll
        for (int r = 0; r < 4; ++r) {
            int qr = wave * 16 + lq * 4 + r;
            int d = dt * 16 + ln;
            Og[(size_t)qr * gstride + d] = (f16)(accO[dt][r] * linv[r]);
        }
    }
}

extern "C" void kernel_launch(void* const* d_in, const int* in_sizes, int n_in,
                              void* d_out, int out_size, void* d_ws, size_t ws_size,
                              hipStream_t stream)
{
    const float* x     = (const float*)d_in[0];
    const int*   seq   = (const int*)d_in[1];
    const float* freqs = (const float*)d_in[3];
    const float* Wq    = (const float*)d_in[4];
    const float* bq    = (const float*)d_in[5];
    const float* Wk    = (const float*)d_in[6];
    const float* bk    = (const float*)d_in[7];
    const float* Wv    = (const float*)d_in[8];
    const float* bv    = (const float*)d_in[9];
    const float* Wo    = (const float*)d_in[10];
    const float* bo    = (const float*)d_in[11];
    const float* gq    = (const float*)d_in[12];
    const float* gk    = (const float*)d_in[13];

    float* out = (float*)d_out;
    const size_t MD = (size_t)MM * DIMM;

    f16* X16 = (f16*)d_ws;          // later reused as O16
    f16* q16 = X16 + MD;
    f16* k16 = X16 + 2 * MD;
    f16* v16 = (f16*)d_out;         // lives in d_out; final GEMM overwrites after last use

    cvt_f16_kernel<<<(int)(MD / (256 * 8)), 256, 0, stream>>>(x, X16, (int)(MD / 8));
    gemm_f16<true><<<(MM / 128) * (3 * DIMM / 128), 256, 0, stream>>>(
        X16, Wq, Wk, Wv, bq, bk, bv, q16, k16, v16, nullptr);
    rmsnorm_rope_f16<<<dim3(MM, 2), 192, 0, stream>>>(q16, k16, gq, gk, freqs);
    flash_attn_f16<<<dim3(SS / 64, NHH, BB), 256, 0, stream>>>(q16, k16, v16, seq, X16);
    gemm_f16<false><<<(MM / 128) * (DIMM / 128), 256, 0, stream>>>(
        X16, Wo, nullptr, nullptr, bo, nullptr, nullptr, nullptr, nullptr, nullptr, out);
}

// Round 6
// 353.683 us; speedup vs baseline: 1.1856x; 1.1856x over previous
//
#include <hip/hip_runtime.h>
#include <cmath>

#define BB   2
#define SS   1024
#define DIMM 3072
#define NHH  24
#define HDD  128
#define MM   (BB * SS)

typedef _Float16 f16;
typedef __attribute__((ext_vector_type(8))) _Float16 half8;
typedef __attribute__((ext_vector_type(4))) float floatx4;
typedef unsigned int u32;
typedef const __attribute__((address_space(1))) u32* gp1;
typedef __attribute__((address_space(3))) u32* lp3;

__device__ __forceinline__ void gload_lds16(const void* g, void* l) {
    __builtin_amdgcn_global_load_lds((gp1)g, (lp3)l, 16, 0, 0);
}

// ---------------- fp32 -> fp16 converter ----------------
__global__ __launch_bounds__(256) void cvt_f16_kernel(
    const float* __restrict__ in, f16* __restrict__ outp, int n8)
{
    int i = blockIdx.x * 256 + threadIdx.x;
    if (i >= n8) return;
    const float4* p = (const float4*)(in + (size_t)i * 8);
    float4 a = p[0], b = p[1];
    half8 h = {(f16)a.x, (f16)a.y, (f16)a.z, (f16)a.w,
               (f16)b.x, (f16)b.y, (f16)b.z, (f16)b.w};
    *(half8*)(outp + (size_t)i * 8) = h;
}

// ---------------- GEMM: C = A16 @ W^T + bias (f16 MFMA, fp32 accum) ----------------
// Depth-2 pipeline: A via global_load_lds into 4 LDS buffers (staged ks+2);
// B fp32->regs (2 static slots) -> f16 ds_write one step ahead (2 LDS buffers).
// One raw s_barrier per K-step; counted vmcnt(12) — loads stay in flight.
template<bool QKV>
__global__ __launch_bounds__(256) void gemm_f16(
    const f16* __restrict__ A,
    const float* __restrict__ W0, const float* __restrict__ W1, const float* __restrict__ W2,
    const float* __restrict__ b0, const float* __restrict__ b1, const float* __restrict__ b2,
    f16* __restrict__ D0, f16* __restrict__ D1, f16* __restrict__ D2,
    float* __restrict__ F)
{
    constexpr int K = DIMM;
    constexpr int NSTEP = K / 32;          // 96 (even)
    constexpr int TS = 128 * 32;
    __shared__ __align__(16) f16 As[4 * TS];   // 32 KB
    __shared__ __align__(16) f16 Bs[2 * TS];   // 16 KB

    const int tid  = threadIdx.x;
    const int lane = tid & 63;
    const int wave = tid >> 6;
    const int wm = wave >> 1, wn = wave & 1;
    const int lr = lane & 15;
    const int lq = lane >> 4;

    // bijective XCD swizzle (grid % 8 == 0: 1152, 384)
    const int id  = blockIdx.x;
    const int cpx = (int)gridDim.x >> 3;
    const int swz = (id & 7) * cpx + (id >> 3);
    const int bm = (swz & 15) << 7;
    const int bn = (swz >> 4) << 7;

    const float* W; const float* bias; f16* D = nullptr;
    int nloc = bn;
    if constexpr (QKV) {
        int sel = bn / DIMM;
        nloc = bn - sel * DIMM;
        W    = sel == 0 ? W0 : (sel == 1 ? W1 : W2);
        bias = sel == 0 ? b0 : (sel == 1 ? b1 : b2);
        D    = sel == 0 ? D0 : (sel == 1 ? D1 : D2);
    } else { W = W0; bias = b0; }

    // B staging coords: rows r0, r0+64; col chunk c8 (linear layout is conflict-free)
    const int r0 = tid >> 2;
    const int c8 = (tid & 3) << 3;
    const float* bp0 = W + (size_t)(nloc + r0) * K + c8;
    const float* bp1 = W + (size_t)(nloc + r0 + 64) * K + c8;

    // A staging via global_load_lds (linear dest = lane*16B)
    const int arow_l = lane >> 2;
    const int acol_l = (lane & 3) << 3;
    const f16* agbase = A + (size_t)bm * K;

    float4 sA[4], sB[4];                   // two static B-reg slots
    auto LOADB = [&](int t, float4* s) {
        const int k0 = t * 32;
        s[0] = *(const float4*)(bp0 + k0); s[1] = *(const float4*)(bp0 + k0 + 4);
        s[2] = *(const float4*)(bp1 + k0); s[3] = *(const float4*)(bp1 + k0 + 4);
    };
    auto STOREB = [&](f16* Bbuf, const float4* s) {
        half8 h0 = {(f16)s[0].x, (f16)s[0].y, (f16)s[0].z, (f16)s[0].w,
                    (f16)s[1].x, (f16)s[1].y, (f16)s[1].z, (f16)s[1].w};
        half8 h1 = {(f16)s[2].x, (f16)s[2].y, (f16)s[2].z, (f16)s[2].w,
                    (f16)s[3].x, (f16)s[3].y, (f16)s[3].z, (f16)s[3].w};
        *(half8*)&Bbuf[r0 * 32 + c8]        = h0;
        *(half8*)&Bbuf[(r0 + 64) * 32 + c8] = h1;
    };
    auto STAGEA = [&](int t, int buf) {
        const int k0 = t * 32;
#pragma unroll
        for (int i = 0; i < 2; ++i) {
            int rbase = wave * 32 + i * 16;
            gload_lds16(agbase + (size_t)(rbase + arow_l) * K + k0 + acol_l,
                        &As[buf * TS + rbase * 32]);
        }
    };

    floatx4 acc[4][4];
#pragma unroll
    for (int i = 0; i < 4; ++i)
#pragma unroll
        for (int j = 0; j < 4; ++j) acc[i][j] = (floatx4){0.f, 0.f, 0.f, 0.f};

    auto COMPUTE = [&](const f16* Ac, const f16* Bc) {
        half8 af[4], bf[4];
#pragma unroll
        for (int i = 0; i < 4; ++i) {
            af[i] = *(const half8*)&Ac[(wm * 64 + i * 16 + lr) * 32 + lq * 8];
            bf[i] = *(const half8*)&Bc[(wn * 64 + i * 16 + lr) * 32 + lq * 8];
        }
        __builtin_amdgcn_s_setprio(1);
#pragma unroll
        for (int mi = 0; mi < 4; ++mi)
#pragma unroll
            for (int ni = 0; ni < 4; ++ni)
                acc[mi][ni] = __builtin_amdgcn_mfma_f32_16x16x32_f16(af[mi], bf[ni], acc[mi][ni], 0, 0, 0);
        __builtin_amdgcn_s_setprio(0);
    };

    // ---- prologue: B(0)->sA, B(1)->sB, A(0)->buf0, A(1)->buf1, B(0)->Bs0 ----
    LOADB(0, sA);
    STAGEA(0, 0);
    LOADB(1, sB);
    STAGEA(1, 1);
    STOREB(&Bs[0], sA);                          // compiler waits sA regs
    asm volatile("s_waitcnt vmcnt(6)" ::: "memory");   // A(0) landed (6 newer in flight)
    asm volatile("s_waitcnt lgkmcnt(0)" ::: "memory");
    __builtin_amdgcn_s_barrier();

    for (int ks = 0; ks < NSTEP; ks += 2) {
        // ---- even sub-iter: compute(A[ks&3], Bs0); stage A(ks+2); B(ks+2)->sA; Bs1 <- sB
        if (ks + 2 < NSTEP) { LOADB(ks + 2, sA); STAGEA(ks + 2, (ks + 2) & 3); }
        asm volatile("s_waitcnt vmcnt(12)" ::: "memory");  // A(ks) complete, newer stay in flight
        __builtin_amdgcn_s_barrier();
        STOREB(&Bs[TS], sB);                     // B(ks+1); readers of Bs1 are 1 barrier back
        COMPUTE(&As[(ks & 3) * TS], &Bs[0]);
        asm volatile("s_waitcnt lgkmcnt(0)" ::: "memory");  // ds_writes visible by next barrier

        // ---- odd sub-iter: compute(A[(ks+1)&3], Bs1); stage A(ks+3); B(ks+3)->sB; Bs0 <- sA
        if (ks + 3 < NSTEP) { LOADB(ks + 3, sB); STAGEA(ks + 3, (ks + 3) & 3); }
        asm volatile("s_waitcnt vmcnt(12)" ::: "memory");
        __builtin_amdgcn_s_barrier();
        if (ks + 2 < NSTEP) STOREB(&Bs[0], sA);  // B(ks+2)
        COMPUTE(&As[((ks + 1) & 3) * TS], &Bs[TS]);
        asm volatile("s_waitcnt lgkmcnt(0)" ::: "memory");
    }

    // epilogue: C/D layout col = lane&15, row = (lane>>4)*4 + reg
    const int crow0 = bm + wm * 64 + (lq << 2);
    const int ccol0 = nloc + wn * 64;
#pragma unroll
    for (int ni = 0; ni < 4; ++ni) {
        const int col = ccol0 + ni * 16 + lr;
        const float bv = bias[col];
#pragma unroll
        for (int mi = 0; mi < 4; ++mi) {
            const int row = crow0 + mi * 16;
#pragma unroll
            for (int r2 = 0; r2 < 4; ++r2) {
                if constexpr (QKV)
                    D[(size_t)(row + r2) * DIMM + col] = (f16)(acc[mi][ni][r2] + bv);
                else
                    F[(size_t)(row + r2) * DIMM + col] = acc[mi][ni][r2] + bv;
            }
        }
    }
}

// ---------------- RMSNorm (over 3072) + RoPE, f16 in/out ----------------
__global__ __launch_bounds__(192) void rmsnorm_rope_f16(
    f16* __restrict__ q, f16* __restrict__ k,
    const float* __restrict__ gq, const float* __restrict__ gk,
    const float* __restrict__ freqs)
{
    f16* t = (blockIdx.y == 0) ? q : k;
    const float* g = (blockIdx.y == 0) ? gq : gk;
    const int row = blockIdx.x;
    const int s = row & (SS - 1);
    const int tid = threadIdx.x;
    f16* base = t + (size_t)row * DIMM + tid * 16;

    half8 v0 = *(const half8*)base;
    half8 v1 = *(const half8*)(base + 8);
    float v[16];
#pragma unroll
    for (int j = 0; j < 8; ++j) { v[j] = (float)v0[j]; v[8 + j] = (float)v1[j]; }

    float ssq = 0.f;
#pragma unroll
    for (int j = 0; j < 16; ++j) ssq += v[j] * v[j];
#pragma unroll
    for (int off = 32; off > 0; off >>= 1) ssq += __shfl_down(ssq, off, 64);
    __shared__ float red[3];
    if ((tid & 63) == 0) red[tid >> 6] = ssq;
    __syncthreads();
    float tot = red[0] + red[1] + red[2];
    float sc = rsqrtf(tot * (1.0f / (float)DIMM) + 1e-6f);

    const float* gp = g + tid * 16;
    float y[16];
#pragma unroll
    for (int j = 0; j < 16; ++j) y[j] = v[j] * sc * gp[j];

#pragma unroll
    for (int p = 0; p < 8; ++p) {
        int idx = tid * 16 + 2 * p;
        int f = (idx & 127) >> 1;
        float ang = freqs[s * 64 + f];
        float cc = cosf(ang), sn = sinf(ang);
        float e = y[2 * p], o = y[2 * p + 1];
        y[2 * p]     = e * cc - o * sn;
        y[2 * p + 1] = e * sn + o * cc;
    }
    half8 o0, o1;
#pragma unroll
    for (int j = 0; j < 8; ++j) { o0[j] = (f16)y[j]; o1[j] = (f16)y[8 + j]; }
    *(half8*)base       = o0;
    *(half8*)(base + 8) = o1;
}

// ---------------- Flash attention: f16 MFMA, wave-parallel online softmax ----------------
__global__ __launch_bounds__(256) void flash_attn_f16(
    const f16* __restrict__ Q, const f16* __restrict__ K,
    const f16* __restrict__ V, const int* __restrict__ seq_lens,
    f16* __restrict__ O)
{
    __shared__ __align__(16) f16 QPs[64 * 128];   // Q tile; wave regions reused as P buffer
    __shared__ __align__(16) f16 Ks[64 * 128];
    __shared__ __align__(16) f16 Vt[128 * 64];    // V transposed [d][j], swizzled

    const int tid  = threadIdx.x;
    const int lane = tid & 63;
    const int wave = tid >> 6;
    const int ln = lane & 15;
    const int lq = lane >> 4;
    const int i0 = blockIdx.x * 64;
    const int h  = blockIdx.y;
    const int b  = blockIdx.z;
    const int slen = seq_lens[b];
    const float scale = 0.08838834764831845f;
    const size_t gstride = NHH * HDD;

    const f16* Qg = Q + ((size_t)(b * SS + i0) * NHH + h) * HDD;
#pragma unroll
    for (int rep = 0; rep < 4; ++rep) {
        int u = tid + rep * 256;
        int r = u >> 4, d0 = (u & 15) << 3;
        half8 qv = *(const half8*)(Qg + (size_t)r * gstride + d0);
        *(half8*)(QPs + r * 128 + (d0 ^ ((r & 7) << 3))) = qv;
    }
    __syncthreads();

    half8 qfrag[4];
    {
        int rq = wave * 16 + ln;
#pragma unroll
        for (int ks = 0; ks < 4; ++ks)
            qfrag[ks] = *(const half8*)(QPs + rq * 128 + ((ks * 32 + lq * 8) ^ ((rq & 7) << 3)));
    }

    floatx4 accO[8];
#pragma unroll
    for (int dt = 0; dt < 8; ++dt) accO[dt] = (floatx4){0.f, 0.f, 0.f, 0.f};
    float mrow[4] = {-3.0e38f, -3.0e38f, -3.0e38f, -3.0e38f};
    float lrow[4] = {0.f, 0.f, 0.f, 0.f};

    const int nT = (slen + 63) >> 6;
    for (int t = 0; t < nT; ++t) {
        const int j0g = t * 64;
        __syncthreads();

        const f16* Kg = K + ((size_t)(b * SS + j0g) * NHH + h) * HDD;
#pragma unroll
        for (int rep = 0; rep < 4; ++rep) {
            int u = tid + rep * 256;
            int r = u >> 4, d0 = (u & 15) << 3;
            half8 kv = *(const half8*)(Kg + (size_t)r * gstride + d0);
            *(half8*)(Ks + r * 128 + (d0 ^ ((r & 7) << 3))) = kv;
        }
        const f16* Vg = V + ((size_t)(b * SS + j0g) * NHH + h) * HDD;
#pragma unroll
        for (int rep = 0; rep < 2; ++rep) {
            int u = tid + rep * 256;
            int jp = u & 31, j0 = jp * 2;
            int d0 = (u >> 5) << 3;
            half8 va = *(const half8*)(Vg + (size_t)j0 * gstride + d0);
            half8 vb = *(const half8*)(Vg + (size_t)(j0 + 1) * gstride + d0);
#pragma unroll
            for (int i = 0; i < 8; ++i) {
                int d = d0 + i;
                union { f16 h[2]; u32 w; } pk;
                pk.h[0] = va[i]; pk.h[1] = vb[i];
                *(u32*)(Vt + d * 64 + (j0 ^ ((d & 7) << 3))) = pk.w;
            }
        }
        __syncthreads();

        // QK^T
        floatx4 acc_s[4];
#pragma unroll
        for (int nt = 0; nt < 4; ++nt) {
            acc_s[nt] = (floatx4){0.f, 0.f, 0.f, 0.f};
            int rk = nt * 16 + ln;
#pragma unroll
            for (int ks = 0; ks < 4; ++ks) {
                half8 kf = *(const half8*)(Ks + rk * 128 + ((ks * 32 + lq * 8) ^ ((rk & 7) << 3)));
                acc_s[nt] = __builtin_amdgcn_mfma_f32_16x16x32_f16(qfrag[ks], kf, acc_s[nt], 0, 0, 0);
            }
        }

        // online softmax (rows = lq*4 + r of this wave's 16)
        float s[4][4];
#pragma unroll
        for (int nt = 0; nt < 4; ++nt) {
            int j = j0g + nt * 16 + ln;
            bool valid = (j < slen);
#pragma unroll
            for (int r = 0; r < 4; ++r)
                s[nt][r] = valid ? acc_s[nt][r] * scale : -3.0e38f;
        }
        float fct[4];
#pragma unroll
        for (int r = 0; r < 4; ++r) {
            float m4 = fmaxf(fmaxf(s[0][r], s[1][r]), fmaxf(s[2][r], s[3][r]));
            m4 = fmaxf(m4, __shfl_xor(m4, 1, 64));
            m4 = fmaxf(m4, __shfl_xor(m4, 2, 64));
            m4 = fmaxf(m4, __shfl_xor(m4, 4, 64));
            m4 = fmaxf(m4, __shfl_xor(m4, 8, 64));
            float mn = fmaxf(mrow[r], m4);
            fct[r] = __expf(mrow[r] - mn);
            mrow[r] = mn;
            float ls = 0.f;
#pragma unroll
            for (int nt = 0; nt < 4; ++nt) {
                float p = __expf(s[nt][r] - mn);
                s[nt][r] = p;
                ls += p;
            }
            ls += __shfl_xor(ls, 1, 64);
            ls += __shfl_xor(ls, 2, 64);
            ls += __shfl_xor(ls, 4, 64);
            ls += __shfl_xor(ls, 8, 64);
            lrow[r] = lrow[r] * fct[r] + ls;
        }

        // write P (f16) into this wave's private region of QPs
#pragma unroll
        for (int nt = 0; nt < 4; ++nt) {
#pragma unroll
            for (int r = 0; r < 4; ++r) {
                int rw = lq * 4 + r;
                int j = nt * 16 + ln;
                QPs[(wave * 16 + rw) * 128 + (j ^ ((rw & 7) << 3))] = (f16)s[nt][r];
            }
        }

        // rescale O
#pragma unroll
        for (int dt = 0; dt < 8; ++dt)
#pragma unroll
            for (int r = 0; r < 4; ++r) accO[dt][r] *= fct[r];

        // PV
        half8 pfrag[2];
#pragma unroll
        for (int js = 0; js < 2; ++js)
            pfrag[js] = *(const half8*)(QPs + (wave * 16 + ln) * 128 + ((js * 32 + lq * 8) ^ ((ln & 7) << 3)));
#pragma unroll
        for (int dt = 0; dt < 8; ++dt) {
            int d = dt * 16 + ln;
#pragma unroll
            for (int js = 0; js < 2; ++js) {
                half8 vf = *(const half8*)(Vt + d * 64 + ((js * 32 + lq * 8) ^ ((d & 7) << 3)));
                accO[dt] = __builtin_amdgcn_mfma_f32_16x16x32_f16(pfrag[js], vf, accO[dt], 0, 0, 0);
            }
        }
    }

    // finalize: /l, write O (f16)
    float linv[4];
#pragma unroll
    for (int r = 0; r < 4; ++r) linv[r] = 1.0f / lrow[r];
    f16* Og = O + ((size_t)(b * SS + i0) * NHH + h) * HDD;
#pragma unroll
    for (int dt = 0; dt < 8; ++dt) {
#pragma unroll
        for (int r = 0; r < 4; ++r) {
            int qr = wave * 16 + lq * 4 + r;
            int d = dt * 16 + ln;
            Og[(size_t)qr * gstride + d] = (f16)(accO[dt][r] * linv[r]);
        }
    }
}

extern "C" void kernel_launch(void* const* d_in, const int* in_sizes, int n_in,
                              void* d_out, int out_size, void* d_ws, size_t ws_size,
                              hipStream_t stream)
{
    const float* x     = (const float*)d_in[0];
    const int*   seq   = (const int*)d_in[1];
    const float* freqs = (const float*)d_in[3];
    const float* Wq    = (const float*)d_in[4];
    const float* bq    = (const float*)d_in[5];
    const float* Wk    = (const float*)d_in[6];
    const float* bk    = (const float*)d_in[7];
    const float* Wv    = (const float*)d_in[8];
    const float* bv    = (const float*)d_in[9];
    const float* Wo    = (const float*)d_in[10];
    const float* bo    = (const float*)d_in[11];
    const float* gq    = (const float*)d_in[12];
    const float* gk    = (const float*)d_in[13];

    float* out = (float*)d_out;
    const size_t MD = (size_t)MM * DIMM;

    f16* X16 = (f16*)d_ws;          // later reused as O16
    f16* q16 = X16 + MD;
    f16* k16 = X16 + 2 * MD;
    f16* v16 = (f16*)d_out;         // lives in d_out; final GEMM overwrites after last use

    cvt_f16_kernel<<<(int)(MD / (256 * 8)), 256, 0, stream>>>(x, X16, (int)(MD / 8));
    gemm_f16<true><<<(MM / 128) * (3 * DIMM / 128), 256, 0, stream>>>(
        X16, Wq, Wk, Wv, bq, bk, bv, q16, k16, v16, nullptr);
    rmsnorm_rope_f16<<<dim3(MM, 2), 192, 0, stream>>>(q16, k16, gq, gk, freqs);
    flash_attn_f16<<<dim3(SS / 64, NHH, BB), 256, 0, stream>>>(q16, k16, v16, seq, X16);
    gemm_f16<false><<<(MM / 128) * (DIMM / 128), 256, 0, stream>>>(
        X16, Wo, nullptr, nullptr, bo, nullptr, nullptr, nullptr, nullptr, nullptr, out);
}